// Round 1
// baseline (230.053 us; speedup 1.0000x reference)
//
#include <hip/hip_runtime.h>

// Depthwise 3x3 conv (diagonal-masked dense conv), fp32.
// x: (S*B=32, C=256, H=64, W=64)  W: (256,256,3,3) -> only diag [c,c,:,:] used.
// One block per (n,c) plane; plane staged in LDS; each global float read once.

#define C_CH 256
#define H_SP 64
#define W_SP 64
#define PLANE (H_SP * W_SP) // 4096 floats = 16 KiB

__global__ __launch_bounds__(256) void dwconv3x3_kernel(
    const float* __restrict__ x,
    const float* __restrict__ Wfull,
    float* __restrict__ out)
{
    __shared__ float tile[PLANE];

    const int p = blockIdx.x;            // plane index in [0, 8192)
    const int c = p & (C_CH - 1);        // channel (inner dim of leading index)
    const float* __restrict__ xp = x + (size_t)p * PLANE;
    float* __restrict__ op = out + (size_t)p * PLANE;

    // 9 diagonal weights, block-uniform: W[((c*C + c)*3 + kh)*3 + kw]
    const float* __restrict__ wp = Wfull + (size_t)c * (C_CH + 1) * 9;
    const float w00 = wp[0], w01 = wp[1], w02 = wp[2];
    const float w10 = wp[3], w11 = wp[4], w12 = wp[5];
    const float w20 = wp[6], w21 = wp[7], w22 = wp[8];

    const int t = threadIdx.x;

    // Stage plane into LDS: 1024 float4s, 256 threads x 4, coalesced.
    const float4* __restrict__ xv = (const float4*)xp;
    float4* tv = (float4*)tile;
#pragma unroll
    for (int i = 0; i < 4; ++i) {
        tv[t + i * 256] = xv[t + i * 256];
    }
    __syncthreads();

    // Each thread computes 4 output float4s (16 outputs).
#pragma unroll
    for (int i = 0; i < 4; ++i) {
        const int f  = t + i * 256;      // float4 index in plane [0,1024)
        const int h  = f >> 4;           // row
        const int w4 = (f & 15) << 2;    // first column of this float4

        float4 acc = make_float4(0.f, 0.f, 0.f, 0.f);

#pragma unroll
        for (int kh = 0; kh < 3; ++kh) {
            const int hh = h + kh - 1;
            if (hh < 0 || hh >= H_SP) continue;
            const float* row = &tile[hh * W_SP];

            const float cm1 = (w4 > 0)         ? row[w4 - 1] : 0.f;
            const float c0  = row[w4];
            const float c1  = row[w4 + 1];
            const float c2  = row[w4 + 2];
            const float c3  = row[w4 + 3];
            const float c4  = (w4 + 4 < W_SP)  ? row[w4 + 4] : 0.f;

            float k0, k1, k2;
            if (kh == 0)      { k0 = w00; k1 = w01; k2 = w02; }
            else if (kh == 1) { k0 = w10; k1 = w11; k2 = w12; }
            else              { k0 = w20; k1 = w21; k2 = w22; }

            acc.x += cm1 * k0 + c0 * k1 + c1 * k2;
            acc.y += c0  * k0 + c1 * k1 + c2 * k2;
            acc.z += c1  * k0 + c2 * k1 + c3 * k2;
            acc.w += c2  * k0 + c3 * k1 + c4 * k2;
        }

        ((float4*)op)[f] = acc;
    }
}

extern "C" void kernel_launch(void* const* d_in, const int* in_sizes, int n_in,
                              void* d_out, int out_size, void* d_ws, size_t ws_size,
                              hipStream_t stream) {
    const float* x = (const float*)d_in[0];
    const float* W = (const float*)d_in[1];
    float* out = (float*)d_out;

    const int n_planes = out_size / PLANE; // 8192
    dwconv3x3_kernel<<<n_planes, 256, 0, stream>>>(x, W, out);
}